// Round 10
// baseline (1613.620 us; speedup 1.0000x reference)
//
#include <hip/hip_runtime.h>
#include <stdint.h>
#include <math.h>

// ---------------------------------------------------------------------------
// DecoderRNN: 2-layer LSTM (B=32, T=64, E=H=512) + vocab projection (V=50257)
//
//   K3 lstm_pipeline: split-K persistent LSTM (round-9 structure, UNCHANGED).
//   K4 logits_gemm  : 256x128xBK64 bf16 MFMA GEMM (round-9, UNCHANGED).
//   DIAGNOSTIC round: two 195-step probes (private buffers) sized to clear
//   the ~237us harness-fill visibility cutoff in the top-5 table:
//     probe A: dosync=1  -> synced cost/step = dur/195
//     probe B: dosync=0  -> work floor/step  = dur/195 (absent => sync-bound)
// ---------------------------------------------------------------------------

typedef unsigned short u16;
typedef __bf16 bf16x8 __attribute__((ext_vector_type(8)));
typedef float  f32x4  __attribute__((ext_vector_type(4)));

#define BATCH   32
#define SEQT    64
#define NSTEP   65
#define EMB     512
#define HID     512
#define VOCAB   50257
#define NWG_LSTM 64
#define PROBE_STEPS 195

static __device__ __forceinline__ u16 f2bf(float f) {
  unsigned u = __float_as_uint(f);
  u += 0x7FFFu + ((u >> 16) & 1u);
  return (u16)(u >> 16);
}

static __device__ __forceinline__ bf16x8 ld_frag(const u16* p16) {
  union { uint4 u; bf16x8 v; } f;
  f.u = *(const uint4*)p16;
  return f.v;
}

// asm 16B loads: result valid only after manual s_waitcnt vmcnt + sched_barrier.
static __device__ __forceinline__ void gload16(uint4* dst, const void* p) {
  asm volatile("global_load_dwordx4 %0, %1, off" : "=v"(*dst) : "v"(p));
}
static __device__ __forceinline__ void gload16_sys(uint4* dst, const void* p) {
  asm volatile("global_load_dwordx4 %0, %1, off sc0 sc1" : "=v"(*dst) : "v"(p));
}
static __device__ __forceinline__ void st_exch32(void* p, unsigned v) {
  (void)__hip_atomic_exchange((unsigned*)p, v, __ATOMIC_RELAXED,
                              __HIP_MEMORY_SCOPE_AGENT);
}

static __device__ __forceinline__ float sigmoid_fast(float x) {
  return 1.0f / (1.0f + __expf(-x));
}
static __device__ __forceinline__ float tanh_fast(float x) {
  return 1.0f - 2.0f / (__expf(2.0f * x) + 1.0f);
}

static __device__ __forceinline__ void wave_poll(const unsigned* slots,
                                                 int base_slot, unsigned tgt,
                                                 int lane) {
  const unsigned* p = slots + (base_slot + (lane & 31)) * 16;
  for (;;) {
    unsigned v = __hip_atomic_load(p, __ATOMIC_RELAXED, __HIP_MEMORY_SCOPE_AGENT);
    if (__all((int)(v >= tgt))) break;
    __builtin_amdgcn_s_sleep(1);
  }
}

// ---------------------------------------------------------------------------
// K1: compact layout dst[t][e>>4][b][e&15]
// ---------------------------------------------------------------------------
__global__ void build_inputs(const float* __restrict__ features,
                             const int*   __restrict__ captions,
                             const float* __restrict__ embed_w,
                             u16* __restrict__ dst) {
  int idx = blockIdx.x * blockDim.x + threadIdx.x;
  const int n = NSTEP * BATCH * EMB;
  if (idx >= n) return;
  int e = idx & (EMB - 1);
  int rem = idx >> 9;
  int b = rem & (BATCH - 1);
  int t = rem >> 5;
  float v;
  if (t == 0) v = features[b * EMB + e];
  else        v = embed_w[(size_t)captions[b * SEQT + (t - 1)] * EMB + e];
  dst[(size_t)t * 16384 + (e >> 4) * 512 + b * 16 + (e & 15)] = f2bf(v);
}

// ---------------------------------------------------------------------------
// K2
// ---------------------------------------------------------------------------
__global__ void cast_bf16(const float* __restrict__ src, u16* __restrict__ dst, int n4) {
  int i = blockIdx.x * blockDim.x + threadIdx.x;
  if (i >= n4) return;
  float4 v = ((const float4*)src)[i];
  ushort4 o;
  o.x = f2bf(v.x); o.y = f2bf(v.y); o.z = f2bf(v.z); o.w = f2bf(v.w);
  ((ushort4*)dst)[i] = o;
}

__global__ void cast_pad_wout(const float* __restrict__ src, u16* __restrict__ dst) {
  int i = blockIdx.x * blockDim.x + threadIdx.x;
  const int n4 = 50304 * 512 / 4;
  const int nsrc4 = VOCAB * 512 / 4;
  if (i >= n4) return;
  ushort4 o;
  if (i < nsrc4) {
    float4 v = ((const float4*)src)[i];
    o.x = f2bf(v.x); o.y = f2bf(v.y); o.z = f2bf(v.z); o.w = f2bf(v.w);
  } else {
    o.x = 0; o.y = 0; o.z = 0; o.w = 0;
  }
  ((ushort4*)dst)[i] = o;
}

// ---------------------------------------------------------------------------
// K3: split-K persistent LSTM (unchanged from round 9)
// ---------------------------------------------------------------------------
#define WAITVM(N) do { asm volatile("s_waitcnt vmcnt(" #N ")" ::: "memory"); \
                       __builtin_amdgcn_sched_barrier(0); } while (0)

__global__ __launch_bounds__(256, 1)
void lstm_pipeline(const u16* __restrict__ inputs_bf,   // [t][32sl][32b][16]
                   const u16* __restrict__ wih0, const u16* __restrict__ whh0,
                   const float* __restrict__ b0,
                   const u16* __restrict__ wih1, const u16* __restrict__ whh1,
                   const float* __restrict__ b1,
                   u16* h0_all, u16* h1_all,
                   u16* __restrict__ A_bf,       // [2048][512] rows (b*64+t)
                   unsigned* slots, int nsteps, int dosync) {
  const int wg    = blockIdx.x;
  const int layer = wg >> 5;
  const int jsl   = wg & 31;
  const int j0    = jsl * 16;
  const int tid   = threadIdx.x;
  const int lane  = tid & 63;
  const int wv    = tid >> 6;
  const int l15   = lane & 15;
  const int lg    = lane >> 4;
  const bool is_h = (wv >= 2);
  const int  wq   = wv & 1;

  const u16*   wih  = layer ? wih1 : wih0;
  const u16*   whh  = layer ? whh1 : whh0;
  const float* bias = layer ? b1 : b0;
  const char* xsrc0 = (const char*)(layer ? h0_all : inputs_bf);
  const char* hsrc0 = (const char*)(layer ? h1_all : h0_all);
  u16*        hdst  = layer ? h1_all : h0_all;
  const int own_base = layer ? 32 : 0;

  __shared__ float gparts[4][4][512];
  __shared__ float bias_l[64];

  if (tid < 64) bias_l[tid] = bias[(tid >> 4) * HID + j0 + (tid & 15)];

  uint4 wreg[8][4];
  {
    const u16* wmat = is_h ? whh : wih;
    const int  kb   = wq * 256;
#pragma unroll
    for (int kc = 0; kc < 8; ++kc) {
#pragma unroll
      for (int g4 = 0; g4 < 4; ++g4) {
        gload16(&wreg[kc][g4],
                wmat + (size_t)(g4 * 512 + j0 + l15) * 512 + kb + kc * 32 + 8 * lg);
      }
      WAITVM(0);
    }
  }
  __syncthreads();

  const int laoff = wq * 16384 + (lg >> 1) * 1024 + l15 * 32 + (lg & 1) * 16;
  const int pw_b  = tid >> 3;
  const int pw_jq = (tid * 2) & 15;
  float creg[2] = {0.f, 0.f};

  for (int t = 0; t < nsteps; ++t) {
    f32x4 acc[2][4];
#pragma unroll
    for (int bh = 0; bh < 2; ++bh)
#pragma unroll
      for (int g4 = 0; g4 < 4; ++g4) acc[bh][g4] = (f32x4){0.f, 0.f, 0.f, 0.f};

    const bool have_a = is_h ? (t > 0) : true;
    if (have_a) {
      const char* src;
      bool sys;
      if (!is_h) {
        src = xsrc0 + (size_t)t * 32768;
        sys = (layer == 1);
        if (layer == 1 && dosync) wave_poll(slots, 0, (unsigned)(t + 1), lane);
      } else {
        src = hsrc0 + (size_t)(t - 1) * 32768;
        sys = true;
        if (dosync) wave_poll(slots, own_base, (unsigned)t, lane);
      }
      uint4 areg[2][8];
      if (sys) {
#pragma unroll
        for (int kc = 0; kc < 8; ++kc) gload16_sys(&areg[0][kc], src + laoff + kc * 2048);
#pragma unroll
        for (int kc = 0; kc < 8; ++kc) gload16_sys(&areg[1][kc], src + laoff + kc * 2048 + 512);
      } else {
#pragma unroll
        for (int kc = 0; kc < 8; ++kc) gload16(&areg[0][kc], src + laoff + kc * 2048);
#pragma unroll
        for (int kc = 0; kc < 8; ++kc) gload16(&areg[1][kc], src + laoff + kc * 2048 + 512);
      }
      WAITVM(8);
#pragma unroll
      for (int kc = 0; kc < 8; ++kc)
#pragma unroll
        for (int g4 = 0; g4 < 4; ++g4)
          acc[0][g4] = __builtin_amdgcn_mfma_f32_16x16x32_bf16(
              *(const bf16x8*)&areg[0][kc], *(const bf16x8*)&wreg[kc][g4],
              acc[0][g4], 0, 0, 0);
      WAITVM(0);
#pragma unroll
      for (int kc = 0; kc < 8; ++kc)
#pragma unroll
        for (int g4 = 0; g4 < 4; ++g4)
          acc[1][g4] = __builtin_amdgcn_mfma_f32_16x16x32_bf16(
              *(const bf16x8*)&areg[1][kc], *(const bf16x8*)&wreg[kc][g4],
              acc[1][g4], 0, 0, 0);
    }
#pragma unroll
    for (int bh = 0; bh < 2; ++bh)
#pragma unroll
      for (int g4 = 0; g4 < 4; ++g4)
#pragma unroll
        for (int rr = 0; rr < 4; ++rr)
          gparts[wv][g4][(bh * 16 + 4 * lg + rr) * 16 + l15] = acc[bh][g4][rr];
    __syncthreads();

    unsigned pk32;
    {
      const int b = pw_b, jq = pw_jq;
      float hv[2];
#pragma unroll
      for (int u = 0; u < 2; ++u) {
        const int jj = jq + u;
        float gi = bias_l[0 * 16 + jj];
        float gf = bias_l[1 * 16 + jj];
        float gg = bias_l[2 * 16 + jj];
        float go = bias_l[3 * 16 + jj];
#pragma unroll
        for (int w = 0; w < 4; ++w) {
          gi += gparts[w][0][b * 16 + jj];
          gf += gparts[w][1][b * 16 + jj];
          gg += gparts[w][2][b * 16 + jj];
          go += gparts[w][3][b * 16 + jj];
        }
        float cn = sigmoid_fast(gf) * creg[u] + sigmoid_fast(gi) * tanh_fast(gg);
        creg[u] = cn;
        hv[u] = sigmoid_fast(go) * tanh_fast(cn);
      }
      pk32 = (unsigned)f2bf(hv[0]) | ((unsigned)f2bf(hv[1]) << 16);
      st_exch32((char*)hdst + (size_t)t * 32768 + jsl * 1024 + b * 32 + jq * 2, pk32);
    }
    asm volatile("s_waitcnt vmcnt(0)" ::: "memory");   // drain h exchange (L3 ack)
    __syncthreads();
    if (tid == 0)
      (void)__hip_atomic_exchange(&slots[wg * 16], (unsigned)(t + 1),
                                  __ATOMIC_RELAXED, __HIP_MEMORY_SCOPE_AGENT);
    if (layer == 1 && t >= 1)
      *(unsigned*)(A_bf + (size_t)(pw_b * SEQT + (t - 1)) * HID + j0 + pw_jq) = pk32;
  }
}

// ---------------------------------------------------------------------------
// K4: logits GEMM (unchanged from round 9)
// ---------------------------------------------------------------------------
__global__ __launch_bounds__(256, 2)
void logits_gemm(const u16* __restrict__ Ag,
                 const u16* __restrict__ Bg,
                 const float* __restrict__ b_out,
                 float* __restrict__ out) {
  const int bid = blockIdx.x;
  const int lin = (bid & 7) * 393 + (bid >> 3);   // bijective: 3144 = 8*393
  const int mt = lin & 7;
  const int nt = lin >> 3;
  const int m0 = mt * 256, v0 = nt * 128;
  const int tid  = threadIdx.x;
  const int lane = tid & 63;
  const int wv   = tid >> 6;
  const int l15  = lane & 15;
  const int lg   = lane >> 4;
  const int wm = (wv & 1) * 128;
  const int wn = (wv >> 1) * 64;

  __shared__ u16 As[256 * 64];   // 32 KB, XOR-swizzled
  __shared__ u16 Bs[128 * 64];   // 16 KB

  f32x4 acc[8][4];
#pragma unroll
  for (int mi = 0; mi < 8; ++mi)
#pragma unroll
    for (int ni = 0; ni < 4; ++ni)
      acc[mi][ni] = (f32x4){0.f, 0.f, 0.f, 0.f};

  const int rswz = (l15 & 7) << 3;

  for (int kt = 0; kt < 8; ++kt) {
#pragma unroll
    for (int c = 0; c < 8; ++c) {
      int chunk = wv * 512 + c * 64 + lane;
      int row   = chunk >> 3;
      int kcs   = ((chunk & 7) ^ (row & 7)) << 3;
      const u16* ga = Ag + (size_t)(m0 + row) * 512 + kt * 64 + kcs;
      u16* la = &As[(wv * 512 + c * 64) * 8];
      __builtin_amdgcn_global_load_lds(
          (const __attribute__((address_space(1))) void*)ga,
          (__attribute__((address_space(3))) void*)la, 16, 0, 0);
    }
#pragma unroll
    for (int c = 0; c < 4; ++c) {
      int chunk = wv * 256 + c * 64 + lane;
      int row   = chunk >> 3;
      int kcs   = ((chunk & 7) ^ (row & 7)) << 3;
      const u16* gb = Bg + (size_t)(v0 + row) * 512 + kt * 64 + kcs;
      u16* lb = &Bs[(wv * 256 + c * 64) * 8];
      __builtin_amdgcn_global_load_lds(
          (const __attribute__((address_space(1))) void*)gb,
          (__attribute__((address_space(3))) void*)lb, 16, 0, 0);
    }
    asm volatile("s_waitcnt vmcnt(0)" ::: "memory");
    __syncthreads();

#pragma unroll
    for (int ks = 0; ks < 2; ++ks) {
      bf16x8 af[8], bfr[4];
#pragma unroll
      for (int i = 0; i < 8; ++i)
        af[i]  = ld_frag(&As[(wm + i * 16 + l15) * 64 + ((ks * 32 + 8 * lg) ^ rswz)]);
#pragma unroll
      for (int i = 0; i < 4; ++i)
        bfr[i] = ld_frag(&Bs[(wn + i * 16 + l15) * 64 + ((ks * 32 + 8 * lg) ^ rswz)]);
#pragma unroll
      for (int mi = 0; mi < 8; ++mi)
#pragma unroll
        for (int ni = 0; ni < 4; ++ni)
          acc[mi][ni] = __builtin_amdgcn_mfma_f32_16x16x32_bf16(
              af[mi], bfr[ni], acc[mi][ni], 0, 0, 0);
    }
    __syncthreads();
  }

  float* tile = (float*)As;
  float bo[4];
#pragma unroll
  for (int ni = 0; ni < 4; ++ni) {
    int v = v0 + wn + ni * 16 + l15;
    bo[ni] = (v < VOCAB) ? b_out[v] : 0.0f;
  }
  const int lrow = (wv & 1) * 16 + 4 * lg;
  const int lcol = (wv >> 1) * 64 + l15;
  for (int mi = 0; mi < 8; ++mi) {
    __syncthreads();
#pragma unroll
    for (int ni = 0; ni < 4; ++ni)
#pragma unroll
      for (int rr = 0; rr < 4; ++rr)
        tile[(lrow + rr) * 132 + lcol + ni * 16] = acc[mi][ni][rr] + bo[ni];
    __syncthreads();
#pragma unroll
    for (int j = 0; j < 16; ++j) {
      int eid = j * 256 + tid;
      int lr  = eid >> 7;
      int c   = eid & 127;
      int grow = m0 + (lr >> 4) * 128 + mi * 16 + (lr & 15);
      int v = v0 + c;
      if (v < VOCAB)
        out[(size_t)grow * VOCAB + v] = tile[lr * 132 + c];
    }
  }
}

// ---------------------------------------------------------------------------
// host
// ---------------------------------------------------------------------------
extern "C" void kernel_launch(void* const* d_in, const int* in_sizes, int n_in,
                              void* d_out, int out_size, void* d_ws, size_t ws_size,
                              hipStream_t stream) {
  const float* features = (const float*)d_in[0];
  const int*   captions = (const int*)d_in[1];
  const float* embed_w  = (const float*)d_in[2];
  const float* w_ih0    = (const float*)d_in[3];
  const float* w_hh0    = (const float*)d_in[4];
  const float* b0       = (const float*)d_in[5];
  const float* w_ih1    = (const float*)d_in[6];
  const float* w_hh1    = (const float*)d_in[7];
  const float* b1       = (const float*)d_in[8];
  const float* w_out    = (const float*)d_in[9];
  const float* b_out    = (const float*)d_in[10];
  float* out = (float*)d_out;

  char* ws = (char*)d_ws;
  size_t off = 0;
  auto alloc = [&](size_t bytes) -> void* {
    void* p = ws + off;
    off = (off + bytes + 255) & ~(size_t)255;
    return p;
  };
  unsigned* slots   = (unsigned*)alloc(64 * 16 * sizeof(unsigned));
  unsigned* slots_p = (unsigned*)alloc(64 * 16 * sizeof(unsigned));
  u16* inputs_bf = (u16*)alloc((size_t)NSTEP * BATCH * EMB * 2);
  u16* wih0_bf   = (u16*)alloc((size_t)4 * HID * EMB * 2);
  u16* whh0_bf   = (u16*)alloc((size_t)4 * HID * HID * 2);
  u16* wih1_bf   = (u16*)alloc((size_t)4 * HID * HID * 2);
  u16* whh1_bf   = (u16*)alloc((size_t)4 * HID * HID * 2);
  u16* wout_bf   = (u16*)alloc((size_t)50304 * HID * 2);
  u16* h0_all    = (u16*)alloc((size_t)NSTEP * BATCH * HID * 2);
  u16* h1_all    = (u16*)alloc((size_t)NSTEP * BATCH * HID * 2);
  u16* A_bf      = (u16*)alloc((size_t)BATCH * SEQT * HID * 2);
  // probe-private buffers sized for PROBE_STEPS
  u16* hp0       = (u16*)alloc((size_t)PROBE_STEPS * 32768);
  u16* hp1       = (u16*)alloc((size_t)PROBE_STEPS * 32768);
  u16* Ap        = (u16*)alloc((size_t)4096 * HID * 2);
  (void)ws_size; (void)in_sizes; (void)n_in; (void)out_size;

  hipMemsetAsync(slots, 0, 64 * 16 * sizeof(unsigned), stream);
  hipMemsetAsync(slots_p, 0, 64 * 16 * sizeof(unsigned), stream);

  {
    int n = NSTEP * BATCH * EMB;
    build_inputs<<<(n + 255) / 256, 256, 0, stream>>>(features, captions, embed_w, inputs_bf);
  }
  {
    int n4 = 4 * HID * EMB / 4;
    cast_bf16<<<(n4 + 255) / 256, 256, 0, stream>>>(w_ih0, wih0_bf, n4);
    cast_bf16<<<(n4 + 255) / 256, 256, 0, stream>>>(w_hh0, whh0_bf, n4);
    cast_bf16<<<(n4 + 255) / 256, 256, 0, stream>>>(w_ih1, wih1_bf, n4);
    cast_bf16<<<(n4 + 255) / 256, 256, 0, stream>>>(w_hh1, whh1_bf, n4);
  }
  {
    int n4 = 50304 * 512 / 4;
    cast_pad_wout<<<(n4 + 255) / 256, 256, 0, stream>>>(w_out, wout_bf);
  }
  // real pipeline (unchanged)
  lstm_pipeline<<<NWG_LSTM, 256, 0, stream>>>(
      inputs_bf, wih0_bf, whh0_bf, b0, wih1_bf, whh1_bf, b1,
      h0_all, h1_all, A_bf, slots, NSTEP, 1);
  logits_gemm<<<3144, 256, 0, stream>>>(A_bf, wout_bf, b_out, out);
  // probe A: 195 steps, synced, private slots -> visible in top-5
  lstm_pipeline<<<NWG_LSTM, 256, 0, stream>>>(
      inputs_bf, wih0_bf, whh0_bf, b0, wih1_bf, whh1_bf, b1,
      hp0, hp1, Ap, slots_p, PROBE_STEPS, 1);
  // probe B: 195 steps, sync-free work floor
  lstm_pipeline<<<NWG_LSTM, 256, 0, stream>>>(
      inputs_bf, wih0_bf, whh0_bf, b0, wih1_bf, whh1_bf, b1,
      hp0, hp1, Ap, slots_p, PROBE_STEPS, 0);
}

// Round 12
// 969.170 us; speedup vs baseline: 1.6650x; 1.6650x over previous
//
#include <hip/hip_runtime.h>
#include <stdint.h>
#include <math.h>

// ---------------------------------------------------------------------------
// DecoderRNN: 2-layer LSTM (B=32, T=64, E=H=512) + vocab projection (V=50257)
//
//   FUSED kernel: blocks 0..63  = split-K persistent LSTM (round-9 structure)
//                 blocks 64..   = logits-GEMM tiles (256x128xBK64) that POLL
//                 the layer-1 slot array and start once their 8-timestep row
//                 range is produced. Logits row (b,t) uses h1[t+1] (reference
//                 drops outs[0]) -- fixed off-by-one from round 11.
// ---------------------------------------------------------------------------

typedef unsigned short u16;
typedef __bf16 bf16x8 __attribute__((ext_vector_type(8)));
typedef float  f32x4  __attribute__((ext_vector_type(4)));

#define BATCH   32
#define SEQT    64
#define NSTEP   65
#define EMB     512
#define HID     512
#define VOCAB   50257
#define NWG_LSTM 64
#define NT_TILES 393          // 50304/128
#define MT_TILES 8            // 2048/256

static __device__ __forceinline__ u16 f2bf(float f) {
  unsigned u = __float_as_uint(f);
  u += 0x7FFFu + ((u >> 16) & 1u);
  return (u16)(u >> 16);
}

static __device__ __forceinline__ bf16x8 ld_frag(const u16* p16) {
  union { uint4 u; bf16x8 v; } f;
  f.u = *(const uint4*)p16;
  return f.v;
}

// asm 16B loads: result valid only after manual s_waitcnt vmcnt + sched_barrier.
static __device__ __forceinline__ void gload16(uint4* dst, const void* p) {
  asm volatile("global_load_dwordx4 %0, %1, off" : "=v"(*dst) : "v"(p));
}
static __device__ __forceinline__ void gload16_sys(uint4* dst, const void* p) {
  asm volatile("global_load_dwordx4 %0, %1, off sc0 sc1" : "=v"(*dst) : "v"(p));
}
static __device__ __forceinline__ void st_exch32(void* p, unsigned v) {
  (void)__hip_atomic_exchange((unsigned*)p, v, __ATOMIC_RELAXED,
                              __HIP_MEMORY_SCOPE_AGENT);
}

static __device__ __forceinline__ float sigmoid_fast(float x) {
  return 1.0f / (1.0f + __expf(-x));
}
static __device__ __forceinline__ float tanh_fast(float x) {
  return 1.0f - 2.0f / (__expf(2.0f * x) + 1.0f);
}

static __device__ __forceinline__ void wave_poll(const unsigned* slots,
                                                 int base_slot, unsigned tgt,
                                                 int lane) {
  const unsigned* p = slots + (base_slot + (lane & 31)) * 16;
  for (;;) {
    unsigned v = __hip_atomic_load(p, __ATOMIC_RELAXED, __HIP_MEMORY_SCOPE_AGENT);
    if (__all((int)(v >= tgt))) break;
    __builtin_amdgcn_s_sleep(1);
  }
}

#define WAITVM(N) do { asm volatile("s_waitcnt vmcnt(" #N ")" ::: "memory"); \
                       __builtin_amdgcn_sched_barrier(0); } while (0)

// ---------------------------------------------------------------------------
// K1: compact layout dst[t][e>>4][b][e&15]
// ---------------------------------------------------------------------------
__global__ void build_inputs(const float* __restrict__ features,
                             const int*   __restrict__ captions,
                             const float* __restrict__ embed_w,
                             u16* __restrict__ dst) {
  int idx = blockIdx.x * blockDim.x + threadIdx.x;
  const int n = NSTEP * BATCH * EMB;
  if (idx >= n) return;
  int e = idx & (EMB - 1);
  int rem = idx >> 9;
  int b = rem & (BATCH - 1);
  int t = rem >> 5;
  float v;
  if (t == 0) v = features[b * EMB + e];
  else        v = embed_w[(size_t)captions[b * SEQT + (t - 1)] * EMB + e];
  dst[(size_t)t * 16384 + (e >> 4) * 512 + b * 16 + (e & 15)] = f2bf(v);
}

// ---------------------------------------------------------------------------
// K2
// ---------------------------------------------------------------------------
__global__ void cast_bf16(const float* __restrict__ src, u16* __restrict__ dst, int n4) {
  int i = blockIdx.x * blockDim.x + threadIdx.x;
  if (i >= n4) return;
  float4 v = ((const float4*)src)[i];
  ushort4 o;
  o.x = f2bf(v.x); o.y = f2bf(v.y); o.z = f2bf(v.z); o.w = f2bf(v.w);
  ((ushort4*)dst)[i] = o;
}

__global__ void cast_pad_wout(const float* __restrict__ src, u16* __restrict__ dst) {
  int i = blockIdx.x * blockDim.x + threadIdx.x;
  const int n4 = 50304 * 512 / 4;
  const int nsrc4 = VOCAB * 512 / 4;
  if (i >= n4) return;
  ushort4 o;
  if (i < nsrc4) {
    float4 v = ((const float4*)src)[i];
    o.x = f2bf(v.x); o.y = f2bf(v.y); o.z = f2bf(v.z); o.w = f2bf(v.w);
  } else {
    o.x = 0; o.y = 0; o.z = 0; o.w = 0;
  }
  ((ushort4*)dst)[i] = o;
}

// ---------------------------------------------------------------------------
// FUSED kernel
// ---------------------------------------------------------------------------
__global__ __launch_bounds__(256, 1)
void fused_lstm_logits(const u16* __restrict__ inputs_bf,   // [t][32sl][32b][16]
                       const u16* __restrict__ wih0, const u16* __restrict__ whh0,
                       const float* __restrict__ b0,
                       const u16* __restrict__ wih1, const u16* __restrict__ whh1,
                       const float* __restrict__ b1,
                       u16* h0_all, u16* h1_all,             // [t][32sl][32b][16]
                       const u16* __restrict__ Bg,           // w_out bf16 [50304][512]
                       const float* __restrict__ b_out,
                       float* __restrict__ out,
                       unsigned* slots) {
  __shared__ char smem[49408];
  const int tid  = threadIdx.x;
  const int lane = tid & 63;
  const int wv   = tid >> 6;
  const int l15  = lane & 15;
  const int lg   = lane >> 4;

  if (blockIdx.x < NWG_LSTM) {
    // =================== LSTM part (round-9 structure) ===================
    const int wg    = blockIdx.x;
    const int layer = wg >> 5;
    const int jsl   = wg & 31;
    const int j0    = jsl * 16;
    const bool is_h = (wv >= 2);
    const int  wq   = wv & 1;

    const u16*   wih  = layer ? wih1 : wih0;
    const u16*   whh  = layer ? whh1 : whh0;
    const float* bias = layer ? b1 : b0;
    const char* xsrc0 = (const char*)(layer ? h0_all : inputs_bf);
    const char* hsrc0 = (const char*)(layer ? h1_all : h0_all);
    u16*        hdst  = layer ? h1_all : h0_all;
    const int own_base = layer ? 32 : 0;

    float* gparts = (float*)smem;              // [w][g][512] = 32 KB
    float* bias_l = (float*)(smem + 49152);    // [64]

    if (tid < 64) bias_l[tid] = bias[(tid >> 4) * HID + j0 + (tid & 15)];

    uint4 wreg[8][4];
    {
      const u16* wmat = is_h ? whh : wih;
      const int  kb   = wq * 256;
#pragma unroll
      for (int kc = 0; kc < 8; ++kc) {
#pragma unroll
        for (int g4 = 0; g4 < 4; ++g4) {
          gload16(&wreg[kc][g4],
                  wmat + (size_t)(g4 * 512 + j0 + l15) * 512 + kb + kc * 32 + 8 * lg);
        }
        WAITVM(0);
      }
    }
    __syncthreads();

    const int laoff = wq * 16384 + (lg >> 1) * 1024 + l15 * 32 + (lg & 1) * 16;
    const int pw_b  = tid >> 3;
    const int pw_jq = (tid * 2) & 15;
    float creg[2] = {0.f, 0.f};

    for (int t = 0; t < NSTEP; ++t) {
      f32x4 acc[2][4];
#pragma unroll
      for (int bh = 0; bh < 2; ++bh)
#pragma unroll
        for (int g4 = 0; g4 < 4; ++g4) acc[bh][g4] = (f32x4){0.f, 0.f, 0.f, 0.f};

      const bool have_a = is_h ? (t > 0) : true;
      if (have_a) {
        const char* src;
        bool sys;
        if (!is_h) {
          src = xsrc0 + (size_t)t * 32768;
          sys = (layer == 1);
          if (layer == 1) wave_poll(slots, 0, (unsigned)(t + 1), lane);
        } else {
          src = hsrc0 + (size_t)(t - 1) * 32768;
          sys = true;
          wave_poll(slots, own_base, (unsigned)t, lane);
        }
        uint4 areg[2][8];
        if (sys) {
#pragma unroll
          for (int kc = 0; kc < 8; ++kc) gload16_sys(&areg[0][kc], src + laoff + kc * 2048);
#pragma unroll
          for (int kc = 0; kc < 8; ++kc) gload16_sys(&areg[1][kc], src + laoff + kc * 2048 + 512);
        } else {
#pragma unroll
          for (int kc = 0; kc < 8; ++kc) gload16(&areg[0][kc], src + laoff + kc * 2048);
#pragma unroll
          for (int kc = 0; kc < 8; ++kc) gload16(&areg[1][kc], src + laoff + kc * 2048 + 512);
        }
        WAITVM(8);
#pragma unroll
        for (int kc = 0; kc < 8; ++kc)
#pragma unroll
          for (int g4 = 0; g4 < 4; ++g4)
            acc[0][g4] = __builtin_amdgcn_mfma_f32_16x16x32_bf16(
                *(const bf16x8*)&areg[0][kc], *(const bf16x8*)&wreg[kc][g4],
                acc[0][g4], 0, 0, 0);
        WAITVM(0);
#pragma unroll
        for (int kc = 0; kc < 8; ++kc)
#pragma unroll
          for (int g4 = 0; g4 < 4; ++g4)
            acc[1][g4] = __builtin_amdgcn_mfma_f32_16x16x32_bf16(
                *(const bf16x8*)&areg[1][kc], *(const bf16x8*)&wreg[kc][g4],
                acc[1][g4], 0, 0, 0);
      }
#pragma unroll
      for (int bh = 0; bh < 2; ++bh)
#pragma unroll
        for (int g4 = 0; g4 < 4; ++g4)
#pragma unroll
          for (int rr = 0; rr < 4; ++rr)
            gparts[(wv * 4 + g4) * 512 + (bh * 16 + 4 * lg + rr) * 16 + l15] = acc[bh][g4][rr];
      __syncthreads();

      {
        const int b = pw_b, jq = pw_jq;
        float hv[2];
#pragma unroll
        for (int u = 0; u < 2; ++u) {
          const int jj = jq + u;
          float gi = bias_l[0 * 16 + jj];
          float gf = bias_l[1 * 16 + jj];
          float gg = bias_l[2 * 16 + jj];
          float go = bias_l[3 * 16 + jj];
#pragma unroll
          for (int w = 0; w < 4; ++w) {
            gi += gparts[(w * 4 + 0) * 512 + b * 16 + jj];
            gf += gparts[(w * 4 + 1) * 512 + b * 16 + jj];
            gg += gparts[(w * 4 + 2) * 512 + b * 16 + jj];
            go += gparts[(w * 4 + 3) * 512 + b * 16 + jj];
          }
          float cn = sigmoid_fast(gf) * creg[u] + sigmoid_fast(gi) * tanh_fast(gg);
          creg[u] = cn;
          hv[u] = sigmoid_fast(go) * tanh_fast(cn);
        }
        unsigned pk32 = (unsigned)f2bf(hv[0]) | ((unsigned)f2bf(hv[1]) << 16);
        st_exch32((char*)hdst + (size_t)t * 32768 + jsl * 1024 + b * 32 + jq * 2, pk32);
      }
      asm volatile("s_waitcnt vmcnt(0)" ::: "memory");   // drain h exchange (L3 ack)
      __syncthreads();
      if (tid == 0)
        (void)__hip_atomic_exchange(&slots[wg * 16], (unsigned)(t + 1),
                                    __ATOMIC_RELAXED, __HIP_MEMORY_SCOPE_AGENT);
    }
    return;
  }

  // =================== GEMM tile part ===================
  // out row (b, t_out) uses h1[t_out + 1]  (reference drops outs[0]).
  // A logical row ra = t_out*32 + b; h index t_h = (ra>>5) + 1.
  const int g  = blockIdx.x - NWG_LSTM;
  const int mt = g / NT_TILES;               // readiness-ordered dispatch
  const int nt = g - mt * NT_TILES;
  const int m0 = mt * 256, v0 = nt * 128;
  const int wm = (wv & 1) * 128;
  const int wn = (wv >> 1) * 64;

  u16* As = (u16*)smem;                      // 32 KB
  u16* Bs = (u16*)(smem + 32768);            // 16 KB
  const char* h1c = (const char*)h1_all;

  f32x4 acc[8][4];
#pragma unroll
  for (int mi = 0; mi < 8; ++mi)
#pragma unroll
    for (int ni = 0; ni < 4; ++ni)
      acc[mi][ni] = (f32x4){0.f, 0.f, 0.f, 0.f};

  const int rswz = (l15 & 7) << 3;

  // need h1[t_h] for t_h in [mt*8+1, mt*8+8] -> all 32 L1 slots >= mt*8+9
  if (tid < 64) wave_poll(slots, 32, (unsigned)(mt * 8 + 9), lane);
  __syncthreads();

  for (int kt = 0; kt < 8; ++kt) {
    // A: bypass loads to regs (consumer L2s hold stale poison lines),
    // pre-swizzled source
    uint4 areg[8];
#pragma unroll
    for (int c = 0; c < 8; ++c) {
      int chunk = wv * 512 + c * 64 + lane;
      int row   = chunk >> 3;
      int kc3   = (chunk & 7) ^ (row & 7);
      int gkc   = kt * 8 + kc3;              // global 16B-chunk 0..63 of the row
      int ra    = m0 + row;                  // t_out = ra>>5, b = ra&31
      const char* pa = h1c + (size_t)((ra >> 5) + 1) * 32768 + (gkc >> 1) * 1024 +
                       (ra & 31) * 32 + (gkc & 1) * 16;
      gload16_sys(&areg[c], pa);
    }
    // B: global_load_lds, pre-swizzled source
#pragma unroll
    for (int c = 0; c < 4; ++c) {
      int chunk = wv * 256 + c * 64 + lane;
      int row   = chunk >> 3;
      int kcs   = ((chunk & 7) ^ (row & 7)) << 3;
      const u16* gb = Bg + (size_t)(v0 + row) * 512 + kt * 64 + kcs;
      u16* lb = &Bs[(wv * 256 + c * 64) * 8];
      __builtin_amdgcn_global_load_lds(
          (const __attribute__((address_space(1))) void*)gb,
          (__attribute__((address_space(3))) void*)lb, 16, 0, 0);
    }
    WAITVM(4);                               // 8 A loads (oldest) done
#pragma unroll
    for (int c = 0; c < 8; ++c)
      *(uint4*)&As[(size_t)(wv * 512 + c * 64 + lane) * 8] = areg[c];
    WAITVM(0);                               // B in LDS
    __syncthreads();

#pragma unroll
    for (int ks = 0; ks < 2; ++ks) {
      bf16x8 af[8], bfr[4];
#pragma unroll
      for (int i = 0; i < 8; ++i)
        af[i]  = ld_frag(&As[(wm + i * 16 + l15) * 64 + ((ks * 32 + 8 * lg) ^ rswz)]);
#pragma unroll
      for (int i = 0; i < 4; ++i)
        bfr[i] = ld_frag(&Bs[(wn + i * 16 + l15) * 64 + ((ks * 32 + 8 * lg) ^ rswz)]);
#pragma unroll
      for (int mi = 0; mi < 8; ++mi)
#pragma unroll
        for (int ni = 0; ni < 4; ++ni)
          acc[mi][ni] = __builtin_amdgcn_mfma_f32_16x16x32_bf16(
              af[mi], bfr[ni], acc[mi][ni], 0, 0, 0);
    }
    __syncthreads();
  }

  // epilogue: LDS transpose -> 256B-contiguous dword stores; row remap b*64+t
  float* tile = (float*)As;
  float bo[4];
#pragma unroll
  for (int ni = 0; ni < 4; ++ni) {
    int v = v0 + wn + ni * 16 + l15;
    bo[ni] = (v < VOCAB) ? b_out[v] : 0.0f;
  }
  const int lrow = (wv & 1) * 16 + 4 * lg;
  const int lcol = (wv >> 1) * 64 + l15;
  for (int mi = 0; mi < 8; ++mi) {
    __syncthreads();
#pragma unroll
    for (int ni = 0; ni < 4; ++ni)
#pragma unroll
      for (int rr = 0; rr < 4; ++rr)
        tile[(lrow + rr) * 132 + lcol + ni * 16] = acc[mi][ni][rr] + bo[ni];
    __syncthreads();
#pragma unroll
    for (int j = 0; j < 16; ++j) {
      int eid = j * 256 + tid;
      int lr  = eid >> 7;
      int c   = eid & 127;
      int ra  = m0 + (lr >> 4) * 128 + mi * 16 + (lr & 15);   // A row = t_out*32+b
      int orow = (ra & 31) * 64 + (ra >> 5);                  // out row = b*64+t_out
      int v = v0 + c;
      if (v < VOCAB)
        out[(size_t)orow * VOCAB + v] = tile[lr * 132 + c];
    }
  }
}

// ---------------------------------------------------------------------------
// host
// ---------------------------------------------------------------------------
extern "C" void kernel_launch(void* const* d_in, const int* in_sizes, int n_in,
                              void* d_out, int out_size, void* d_ws, size_t ws_size,
                              hipStream_t stream) {
  const float* features = (const float*)d_in[0];
  const int*   captions = (const int*)d_in[1];
  const float* embed_w  = (const float*)d_in[2];
  const float* w_ih0    = (const float*)d_in[3];
  const float* w_hh0    = (const float*)d_in[4];
  const float* b0       = (const float*)d_in[5];
  const float* w_ih1    = (const float*)d_in[6];
  const float* w_hh1    = (const float*)d_in[7];
  const float* b1       = (const float*)d_in[8];
  const float* w_out    = (const float*)d_in[9];
  const float* b_out    = (const float*)d_in[10];
  float* out = (float*)d_out;

  char* ws = (char*)d_ws;
  size_t off = 0;
  auto alloc = [&](size_t bytes) -> void* {
    void* p = ws + off;
    off = (off + bytes + 255) & ~(size_t)255;
    return p;
  };
  unsigned* slots = (unsigned*)alloc(64 * 16 * sizeof(unsigned));
  u16* inputs_bf = (u16*)alloc((size_t)NSTEP * BATCH * EMB * 2);
  u16* wih0_bf   = (u16*)alloc((size_t)4 * HID * EMB * 2);
  u16* whh0_bf   = (u16*)alloc((size_t)4 * HID * HID * 2);
  u16* wih1_bf   = (u16*)alloc((size_t)4 * HID * HID * 2);
  u16* whh1_bf   = (u16*)alloc((size_t)4 * HID * HID * 2);
  u16* wout_bf   = (u16*)alloc((size_t)50304 * HID * 2);
  u16* h0_all    = (u16*)alloc((size_t)NSTEP * BATCH * HID * 2);
  u16* h1_all    = (u16*)alloc((size_t)NSTEP * BATCH * HID * 2);
  (void)ws_size; (void)in_sizes; (void)n_in; (void)out_size;

  hipMemsetAsync(slots, 0, 64 * 16 * sizeof(unsigned), stream);

  {
    int n = NSTEP * BATCH * EMB;
    build_inputs<<<(n + 255) / 256, 256, 0, stream>>>(features, captions, embed_w, inputs_bf);
  }
  {
    int n4 = 4 * HID * EMB / 4;
    cast_bf16<<<(n4 + 255) / 256, 256, 0, stream>>>(w_ih0, wih0_bf, n4);
    cast_bf16<<<(n4 + 255) / 256, 256, 0, stream>>>(w_hh0, whh0_bf, n4);
    cast_bf16<<<(n4 + 255) / 256, 256, 0, stream>>>(w_ih1, wih1_bf, n4);
    cast_bf16<<<(n4 + 255) / 256, 256, 0, stream>>>(w_hh1, whh1_bf, n4);
  }
  {
    int n4 = 50304 * 512 / 4;
    cast_pad_wout<<<(n4 + 255) / 256, 256, 0, stream>>>(w_out, wout_bf);
  }
  // fused: 64 LSTM blocks (dispatched first) + 3144 GEMM tile blocks
  fused_lstm_logits<<<NWG_LSTM + MT_TILES * NT_TILES, 256, 0, stream>>>(
      inputs_bf, wih0_bf, whh0_bf, b0, wih1_bf, whh1_bf, b1,
      h0_all, h1_all, wout_bf, b_out, out, slots);
}

// Round 13
// 456.517 us; speedup vs baseline: 3.5346x; 2.1230x over previous
//
#include <hip/hip_runtime.h>
#include <stdint.h>
#include <math.h>

// ---------------------------------------------------------------------------
// DecoderRNN: 2-layer LSTM (B=32, T=64, E=H=512) + vocab projection (V=50257)
//
//   FUSED kernel: blocks 0..63  = split-K persistent LSTM (round-9 structure)
//                 blocks 64..   = logits-GEMM tiles (128x128xBK64) that POLL
//                 the layer-1 slot array; row (b,t) uses h1[t+1].
//   Round-13 changes (GEMM branch only): 128x128 tiles (acc=64 VGPR, no
//   spill), A staged via plain global_load_lds (write-once + poll-gated +
//   dispatch-boundary L2 invalidate makes cached reads safe; enables
//   same-XCD A reuse through L2).
// ---------------------------------------------------------------------------

typedef unsigned short u16;
typedef __bf16 bf16x8 __attribute__((ext_vector_type(8)));
typedef float  f32x4  __attribute__((ext_vector_type(4)));

#define BATCH   32
#define SEQT    64
#define NSTEP   65
#define EMB     512
#define HID     512
#define VOCAB   50257
#define NWG_LSTM 64
#define NT_TILES 393          // 50304/128
#define MT_TILES 16           // 2048/128

static __device__ __forceinline__ u16 f2bf(float f) {
  unsigned u = __float_as_uint(f);
  u += 0x7FFFu + ((u >> 16) & 1u);
  return (u16)(u >> 16);
}

static __device__ __forceinline__ bf16x8 ld_frag(const u16* p16) {
  union { uint4 u; bf16x8 v; } f;
  f.u = *(const uint4*)p16;
  return f.v;
}

// asm 16B loads: result valid only after manual s_waitcnt vmcnt + sched_barrier.
static __device__ __forceinline__ void gload16(uint4* dst, const void* p) {
  asm volatile("global_load_dwordx4 %0, %1, off" : "=v"(*dst) : "v"(p));
}
static __device__ __forceinline__ void gload16_sys(uint4* dst, const void* p) {
  asm volatile("global_load_dwordx4 %0, %1, off sc0 sc1" : "=v"(*dst) : "v"(p));
}
static __device__ __forceinline__ void st_exch32(void* p, unsigned v) {
  (void)__hip_atomic_exchange((unsigned*)p, v, __ATOMIC_RELAXED,
                              __HIP_MEMORY_SCOPE_AGENT);
}

static __device__ __forceinline__ float sigmoid_fast(float x) {
  return 1.0f / (1.0f + __expf(-x));
}
static __device__ __forceinline__ float tanh_fast(float x) {
  return 1.0f - 2.0f / (__expf(2.0f * x) + 1.0f);
}

static __device__ __forceinline__ void wave_poll(const unsigned* slots,
                                                 int base_slot, unsigned tgt,
                                                 int lane) {
  const unsigned* p = slots + (base_slot + (lane & 31)) * 16;
  for (;;) {
    unsigned v = __hip_atomic_load(p, __ATOMIC_RELAXED, __HIP_MEMORY_SCOPE_AGENT);
    if (__all((int)(v >= tgt))) break;
    __builtin_amdgcn_s_sleep(1);
  }
}

#define WAITVM(N) do { asm volatile("s_waitcnt vmcnt(" #N ")" ::: "memory"); \
                       __builtin_amdgcn_sched_barrier(0); } while (0)

// ---------------------------------------------------------------------------
// K1: compact layout dst[t][e>>4][b][e&15]
// ---------------------------------------------------------------------------
__global__ void build_inputs(const float* __restrict__ features,
                             const int*   __restrict__ captions,
                             const float* __restrict__ embed_w,
                             u16* __restrict__ dst) {
  int idx = blockIdx.x * blockDim.x + threadIdx.x;
  const int n = NSTEP * BATCH * EMB;
  if (idx >= n) return;
  int e = idx & (EMB - 1);
  int rem = idx >> 9;
  int b = rem & (BATCH - 1);
  int t = rem >> 5;
  float v;
  if (t == 0) v = features[b * EMB + e];
  else        v = embed_w[(size_t)captions[b * SEQT + (t - 1)] * EMB + e];
  dst[(size_t)t * 16384 + (e >> 4) * 512 + b * 16 + (e & 15)] = f2bf(v);
}

// ---------------------------------------------------------------------------
// K2
// ---------------------------------------------------------------------------
__global__ void cast_bf16(const float* __restrict__ src, u16* __restrict__ dst, int n4) {
  int i = blockIdx.x * blockDim.x + threadIdx.x;
  if (i >= n4) return;
  float4 v = ((const float4*)src)[i];
  ushort4 o;
  o.x = f2bf(v.x); o.y = f2bf(v.y); o.z = f2bf(v.z); o.w = f2bf(v.w);
  ((ushort4*)dst)[i] = o;
}

__global__ void cast_pad_wout(const float* __restrict__ src, u16* __restrict__ dst) {
  int i = blockIdx.x * blockDim.x + threadIdx.x;
  const int n4 = 50304 * 512 / 4;
  const int nsrc4 = VOCAB * 512 / 4;
  if (i >= n4) return;
  ushort4 o;
  if (i < nsrc4) {
    float4 v = ((const float4*)src)[i];
    o.x = f2bf(v.x); o.y = f2bf(v.y); o.z = f2bf(v.z); o.w = f2bf(v.w);
  } else {
    o.x = 0; o.y = 0; o.z = 0; o.w = 0;
  }
  ((ushort4*)dst)[i] = o;
}

// ---------------------------------------------------------------------------
// FUSED kernel
// ---------------------------------------------------------------------------
__global__ __launch_bounds__(256, 1)
void fused_lstm_logits(const u16* __restrict__ inputs_bf,   // [t][32sl][32b][16]
                       const u16* __restrict__ wih0, const u16* __restrict__ whh0,
                       const float* __restrict__ b0,
                       const u16* __restrict__ wih1, const u16* __restrict__ whh1,
                       const float* __restrict__ b1,
                       u16* h0_all, u16* h1_all,             // [t][32sl][32b][16]
                       const u16* __restrict__ Bg,           // w_out bf16 [50304][512]
                       const float* __restrict__ b_out,
                       float* __restrict__ out,
                       unsigned* slots) {
  __shared__ char smem[49408];
  const int tid  = threadIdx.x;
  const int lane = tid & 63;
  const int wv   = tid >> 6;
  const int l15  = lane & 15;
  const int lg   = lane >> 4;

  if (blockIdx.x < NWG_LSTM) {
    // =================== LSTM part (round-9 structure, unchanged) ===========
    const int wg    = blockIdx.x;
    const int layer = wg >> 5;
    const int jsl   = wg & 31;
    const int j0    = jsl * 16;
    const bool is_h = (wv >= 2);
    const int  wq   = wv & 1;

    const u16*   wih  = layer ? wih1 : wih0;
    const u16*   whh  = layer ? whh1 : whh0;
    const float* bias = layer ? b1 : b0;
    const char* xsrc0 = (const char*)(layer ? h0_all : inputs_bf);
    const char* hsrc0 = (const char*)(layer ? h1_all : h0_all);
    u16*        hdst  = layer ? h1_all : h0_all;
    const int own_base = layer ? 32 : 0;

    float* gparts = (float*)smem;              // [w][g][512] = 32 KB
    float* bias_l = (float*)(smem + 49152);    // [64]

    if (tid < 64) bias_l[tid] = bias[(tid >> 4) * HID + j0 + (tid & 15)];

    uint4 wreg[8][4];
    {
      const u16* wmat = is_h ? whh : wih;
      const int  kb   = wq * 256;
#pragma unroll
      for (int kc = 0; kc < 8; ++kc) {
#pragma unroll
        for (int g4 = 0; g4 < 4; ++g4) {
          gload16(&wreg[kc][g4],
                  wmat + (size_t)(g4 * 512 + j0 + l15) * 512 + kb + kc * 32 + 8 * lg);
        }
        WAITVM(0);
      }
    }
    __syncthreads();

    const int laoff = wq * 16384 + (lg >> 1) * 1024 + l15 * 32 + (lg & 1) * 16;
    const int pw_b  = tid >> 3;
    const int pw_jq = (tid * 2) & 15;
    float creg[2] = {0.f, 0.f};

    for (int t = 0; t < NSTEP; ++t) {
      f32x4 acc[2][4];
#pragma unroll
      for (int bh = 0; bh < 2; ++bh)
#pragma unroll
        for (int g4 = 0; g4 < 4; ++g4) acc[bh][g4] = (f32x4){0.f, 0.f, 0.f, 0.f};

      const bool have_a = is_h ? (t > 0) : true;
      if (have_a) {
        const char* src;
        bool sys;
        if (!is_h) {
          src = xsrc0 + (size_t)t * 32768;
          sys = (layer == 1);
          if (layer == 1) wave_poll(slots, 0, (unsigned)(t + 1), lane);
        } else {
          src = hsrc0 + (size_t)(t - 1) * 32768;
          sys = true;
          wave_poll(slots, own_base, (unsigned)t, lane);
        }
        uint4 areg[2][8];
        if (sys) {
#pragma unroll
          for (int kc = 0; kc < 8; ++kc) gload16_sys(&areg[0][kc], src + laoff + kc * 2048);
#pragma unroll
          for (int kc = 0; kc < 8; ++kc) gload16_sys(&areg[1][kc], src + laoff + kc * 2048 + 512);
        } else {
#pragma unroll
          for (int kc = 0; kc < 8; ++kc) gload16(&areg[0][kc], src + laoff + kc * 2048);
#pragma unroll
          for (int kc = 0; kc < 8; ++kc) gload16(&areg[1][kc], src + laoff + kc * 2048 + 512);
        }
        WAITVM(8);
#pragma unroll
        for (int kc = 0; kc < 8; ++kc)
#pragma unroll
          for (int g4 = 0; g4 < 4; ++g4)
            acc[0][g4] = __builtin_amdgcn_mfma_f32_16x16x32_bf16(
                *(const bf16x8*)&areg[0][kc], *(const bf16x8*)&wreg[kc][g4],
                acc[0][g4], 0, 0, 0);
        WAITVM(0);
#pragma unroll
        for (int kc = 0; kc < 8; ++kc)
#pragma unroll
          for (int g4 = 0; g4 < 4; ++g4)
            acc[1][g4] = __builtin_amdgcn_mfma_f32_16x16x32_bf16(
                *(const bf16x8*)&areg[1][kc], *(const bf16x8*)&wreg[kc][g4],
                acc[1][g4], 0, 0, 0);
      }
#pragma unroll
      for (int bh = 0; bh < 2; ++bh)
#pragma unroll
        for (int g4 = 0; g4 < 4; ++g4)
#pragma unroll
          for (int rr = 0; rr < 4; ++rr)
            gparts[(wv * 4 + g4) * 512 + (bh * 16 + 4 * lg + rr) * 16 + l15] = acc[bh][g4][rr];
      __syncthreads();

      {
        const int b = pw_b, jq = pw_jq;
        float hv[2];
#pragma unroll
        for (int u = 0; u < 2; ++u) {
          const int jj = jq + u;
          float gi = bias_l[0 * 16 + jj];
          float gf = bias_l[1 * 16 + jj];
          float gg = bias_l[2 * 16 + jj];
          float go = bias_l[3 * 16 + jj];
#pragma unroll
          for (int w = 0; w < 4; ++w) {
            gi += gparts[(w * 4 + 0) * 512 + b * 16 + jj];
            gf += gparts[(w * 4 + 1) * 512 + b * 16 + jj];
            gg += gparts[(w * 4 + 2) * 512 + b * 16 + jj];
            go += gparts[(w * 4 + 3) * 512 + b * 16 + jj];
          }
          float cn = sigmoid_fast(gf) * creg[u] + sigmoid_fast(gi) * tanh_fast(gg);
          creg[u] = cn;
          hv[u] = sigmoid_fast(go) * tanh_fast(cn);
        }
        unsigned pk32 = (unsigned)f2bf(hv[0]) | ((unsigned)f2bf(hv[1]) << 16);
        st_exch32((char*)hdst + (size_t)t * 32768 + jsl * 1024 + b * 32 + jq * 2, pk32);
      }
      asm volatile("s_waitcnt vmcnt(0)" ::: "memory");   // drain h exchange (L3 ack)
      __syncthreads();
      if (tid == 0)
        (void)__hip_atomic_exchange(&slots[wg * 16], (unsigned)(t + 1),
                                    __ATOMIC_RELAXED, __HIP_MEMORY_SCOPE_AGENT);
    }
    return;
  }

  // =================== GEMM tile part (128x128, no-spill) ===================
  // out row (b, t_out) uses h1[t_out + 1]; A row ra = t_out*32 + b.
  const int g  = blockIdx.x - NWG_LSTM;
  const int mt = g / NT_TILES;               // 0..15, readiness-ordered
  const int nt = g - mt * NT_TILES;
  const int m0 = mt * 128, v0 = nt * 128;
  const int wm = (wv & 1) * 64;
  const int wn = (wv >> 1) * 64;

  u16* As = (u16*)smem;                      // 16 KB
  u16* Bs = (u16*)(smem + 16384);            // 16 KB
  const char* h1c = (const char*)h1_all;

  f32x4 acc[4][4];
#pragma unroll
  for (int mi = 0; mi < 4; ++mi)
#pragma unroll
    for (int ni = 0; ni < 4; ++ni)
      acc[mi][ni] = (f32x4){0.f, 0.f, 0.f, 0.f};

  const int rswz = (l15 & 7) << 3;

  // need h1[t_h], t_h in [mt*4+1, mt*4+4] -> all 32 L1 slots >= mt*4+5
  if (tid < 64) wave_poll(slots, 32, (unsigned)(mt * 4 + 5), lane);
  __syncthreads();

  for (int kt = 0; kt < 8; ++kt) {
    // A: plain global_load_lds from h1_all, pre-swizzled source (rule #21)
#pragma unroll
    for (int c = 0; c < 4; ++c) {
      int chunk = wv * 256 + c * 64 + lane;   // 0..1023
      int row   = chunk >> 3;                 // 0..127
      int kc3   = (chunk & 7) ^ (row & 7);
      int gkc   = kt * 8 + kc3;               // global 16B-chunk 0..63
      int ra    = m0 + row;                   // t_out = ra>>5, b = ra&31
      const char* pa = h1c + (size_t)((ra >> 5) + 1) * 32768 + (gkc >> 1) * 1024 +
                       (ra & 31) * 32 + (gkc & 1) * 16;
      u16* la = &As[(wv * 256 + c * 64) * 8];
      __builtin_amdgcn_global_load_lds(
          (const __attribute__((address_space(1))) void*)pa,
          (__attribute__((address_space(3))) void*)la, 16, 0, 0);
    }
    // B: global_load_lds, pre-swizzled source
#pragma unroll
    for (int c = 0; c < 4; ++c) {
      int chunk = wv * 256 + c * 64 + lane;
      int row   = chunk >> 3;
      int kcs   = ((chunk & 7) ^ (row & 7)) << 3;
      const u16* gb = Bg + (size_t)(v0 + row) * 512 + kt * 64 + kcs;
      u16* lb = &Bs[(wv * 256 + c * 64) * 8];
      __builtin_amdgcn_global_load_lds(
          (const __attribute__((address_space(1))) void*)gb,
          (__attribute__((address_space(3))) void*)lb, 16, 0, 0);
    }
    WAITVM(0);
    __syncthreads();

#pragma unroll
    for (int ks = 0; ks < 2; ++ks) {
      bf16x8 af[4], bfr[4];
#pragma unroll
      for (int i = 0; i < 4; ++i) {
        af[i]  = ld_frag(&As[(wm + i * 16 + l15) * 64 + ((ks * 32 + 8 * lg) ^ rswz)]);
        bfr[i] = ld_frag(&Bs[(wn + i * 16 + l15) * 64 + ((ks * 32 + 8 * lg) ^ rswz)]);
      }
#pragma unroll
      for (int mi = 0; mi < 4; ++mi)
#pragma unroll
        for (int ni = 0; ni < 4; ++ni)
          acc[mi][ni] = __builtin_amdgcn_mfma_f32_16x16x32_bf16(
              af[mi], bfr[ni], acc[mi][ni], 0, 0, 0);
    }
    __syncthreads();
  }

  // epilogue: LDS transpose -> 256B-contiguous dword stores; row remap b*64+t
  float* tile = (float*)smem;                // 32x132 f32 = 16.9 KB
  float bo[4];
#pragma unroll
  for (int ni = 0; ni < 4; ++ni) {
    int v = v0 + wn + ni * 16 + l15;
    bo[ni] = (v < VOCAB) ? b_out[v] : 0.0f;
  }
  const int lrow = (wv & 1) * 16 + 4 * lg;
  const int lcol = (wv >> 1) * 64 + l15;
  for (int mi = 0; mi < 4; ++mi) {
    __syncthreads();
#pragma unroll
    for (int ni = 0; ni < 4; ++ni)
#pragma unroll
      for (int rr = 0; rr < 4; ++rr)
        tile[(lrow + rr) * 132 + lcol + ni * 16] = acc[mi][ni][rr] + bo[ni];
    __syncthreads();
#pragma unroll
    for (int j = 0; j < 16; ++j) {
      int eid = j * 256 + tid;
      int lr  = eid >> 7;                     // 0..31
      int c   = eid & 127;
      int ra  = m0 + (lr >> 4) * 64 + mi * 16 + (lr & 15);   // A row = t_out*32+b
      int orow = (ra & 31) * 64 + (ra >> 5);                 // out row = b*64+t_out
      int v = v0 + c;
      if (v < VOCAB)
        out[(size_t)orow * VOCAB + v] = tile[lr * 132 + c];
    }
  }
}

// ---------------------------------------------------------------------------
// host
// ---------------------------------------------------------------------------
extern "C" void kernel_launch(void* const* d_in, const int* in_sizes, int n_in,
                              void* d_out, int out_size, void* d_ws, size_t ws_size,
                              hipStream_t stream) {
  const float* features = (const float*)d_in[0];
  const int*   captions = (const int*)d_in[1];
  const float* embed_w  = (const float*)d_in[2];
  const float* w_ih0    = (const float*)d_in[3];
  const float* w_hh0    = (const float*)d_in[4];
  const float* b0       = (const float*)d_in[5];
  const float* w_ih1    = (const float*)d_in[6];
  const float* w_hh1    = (const float*)d_in[7];
  const float* b1       = (const float*)d_in[8];
  const float* w_out    = (const float*)d_in[9];
  const float* b_out    = (const float*)d_in[10];
  float* out = (float*)d_out;

  char* ws = (char*)d_ws;
  size_t off = 0;
  auto alloc = [&](size_t bytes) -> void* {
    void* p = ws + off;
    off = (off + bytes + 255) & ~(size_t)255;
    return p;
  };
  unsigned* slots = (unsigned*)alloc(64 * 16 * sizeof(unsigned));
  u16* inputs_bf = (u16*)alloc((size_t)NSTEP * BATCH * EMB * 2);
  u16* wih0_bf   = (u16*)alloc((size_t)4 * HID * EMB * 2);
  u16* whh0_bf   = (u16*)alloc((size_t)4 * HID * HID * 2);
  u16* wih1_bf   = (u16*)alloc((size_t)4 * HID * HID * 2);
  u16* whh1_bf   = (u16*)alloc((size_t)4 * HID * HID * 2);
  u16* wout_bf   = (u16*)alloc((size_t)50304 * HID * 2);
  u16* h0_all    = (u16*)alloc((size_t)NSTEP * BATCH * HID * 2);
  u16* h1_all    = (u16*)alloc((size_t)NSTEP * BATCH * HID * 2);
  (void)ws_size; (void)in_sizes; (void)n_in; (void)out_size;

  hipMemsetAsync(slots, 0, 64 * 16 * sizeof(unsigned), stream);

  {
    int n = NSTEP * BATCH * EMB;
    build_inputs<<<(n + 255) / 256, 256, 0, stream>>>(features, captions, embed_w, inputs_bf);
  }
  {
    int n4 = 4 * HID * EMB / 4;
    cast_bf16<<<(n4 + 255) / 256, 256, 0, stream>>>(w_ih0, wih0_bf, n4);
    cast_bf16<<<(n4 + 255) / 256, 256, 0, stream>>>(w_hh0, whh0_bf, n4);
    cast_bf16<<<(n4 + 255) / 256, 256, 0, stream>>>(w_ih1, wih1_bf, n4);
    cast_bf16<<<(n4 + 255) / 256, 256, 0, stream>>>(w_hh1, whh1_bf, n4);
  }
  {
    int n4 = 50304 * 512 / 4;
    cast_pad_wout<<<(n4 + 255) / 256, 256, 0, stream>>>(w_out, wout_bf);
  }
  // fused: 64 LSTM blocks (dispatched first) + 6288 GEMM tile blocks
  fused_lstm_logits<<<NWG_LSTM + MT_TILES * NT_TILES, 256, 0, stream>>>(
      inputs_bf, wih0_bf, whh0_bf, b0, wih1_bf, whh1_bf, b1,
      h0_all, h1_all, wout_bf, b_out, out, slots);
}